// Round 10
// baseline (77.370 us; speedup 1.0000x reference)
//
#include <hip/hip_runtime.h>
#include <math.h>

// Base = round-9 kernel (best: 75.27 us total).  Layout unchanged:
// 8 complex amps/lane, 2 batch elements/wave64 (one per 32-lane half).
// Amp p = l<<3 | r, l = lane&31 (5 lane bits, wires 0..4), r = reg (3 bits:
// bit2=wire5=pack axis, bit1=wire6, bit0=wire7).  Regs packed as float2
// along reg bit2.  asm v_pk_* math; prep kernel for batch-invariant coeffs;
// cycle-1 closed-form product state; folded measurement (u3#5,crx10,u3#6).
//
// Round 10 changes (pipe assignment test):
//  1. ALL cross-lane shuffles now ds_swizzle (DS pipe) instead of DPP
//     (VALU pipe).  Hypothesis: VALU issue is the bottleneck (66% ceiling),
//     DS pipe is ~35% busy -> swizzles issue in VALU gaps for free.
//  2. Ring CNOT pack-swap + swap42 fused into one 16-cndmask permutation
//     (eliminates 8 movs per ring).
//
// Lane-bit lazy GF(2) CNOT relabeling (validated r4..r9):
//  C2 U:(16,24)(24,12)(28,6)(30,3)(31,1) lr-ctrl 21  rl-V 20
//  C3 U:(16,20)(8,10)(20,5)(10,2)(21,1)  lr-ctrl 19  rl-V 30
//  C4 U:(16,30)(24,15)(12,7)(6,3)(19,1)  lr-ctrl 17  rl-V 17
//  QCNN: w0(16,17) w1(8,8) w2(4,4) w3(2,2) w4(17,1); reg wires 5,6,7=bits 2,1,0.

typedef float v2f __attribute__((ext_vector_type(2)));

__device__ __forceinline__ v2f pkmul(v2f a, v2f b) {
  v2f d; asm("v_pk_mul_f32 %0, %1, %2" : "=v"(d) : "v"(a), "v"(b)); return d;
}
__device__ __forceinline__ v2f pkfma(v2f a, v2f b, v2f c) {
  v2f d; asm("v_pk_fma_f32 %0, %1, %2, %3" : "=v"(d) : "v"(a), "v"(b), "v"(c)); return d;
}
__device__ __forceinline__ v2f pkmul_lo1(v2f a, v2f b) {
  v2f d; asm("v_pk_mul_f32 %0, %1, %2 op_sel:[0,0] op_sel_hi:[1,0]"
             : "=v"(d) : "v"(a), "v"(b)); return d;
}
__device__ __forceinline__ v2f pkfma_lo1(v2f a, v2f b, v2f c) {
  v2f d; asm("v_pk_fma_f32 %0, %1, %2, %3 op_sel:[0,0,0] op_sel_hi:[1,0,1]"
             : "=v"(d) : "v"(a), "v"(b), "v"(c)); return d;
}
__device__ __forceinline__ v2f pkfma_hi1(v2f a, v2f b, v2f c) {
  v2f d; asm("v_pk_fma_f32 %0, %1, %2, %3 op_sel:[0,1,0] op_sel_hi:[1,1,1]"
             : "=v"(d) : "v"(a), "v"(b), "v"(c)); return d;
}
__device__ __forceinline__ v2f pkfma_sw1(v2f a, v2f b, v2f c) {
  v2f d; asm("v_pk_fma_f32 %0, %1, %2, %3 op_sel:[0,1,0] op_sel_hi:[1,0,1]"
             : "=v"(d) : "v"(a), "v"(b), "v"(c)); return d;
}
__device__ __forceinline__ v2f dup(float x) { return (v2f){x, x}; }

// ALL shuffles on the DS pipe (single ds_swizzle; every mask < 32 here).
template <int M>
__device__ __forceinline__ float shxm(float v) {
  static_assert(M < 32, "mask must fit 5 lane bits");
  return __int_as_float(__builtin_amdgcn_ds_swizzle(
      __float_as_int(v), (M << 10) | 0x1F));
}
template <int M>
__device__ __forceinline__ v2f shf2(v2f a) {
  return (v2f){shxm<M>(a.x), shxm<M>(a.y)};
}

struct G1 { float r00, i00, r01, i01, r10, i10, r11, i11; };

// generic 2x2 complex gate on a reg pair (lo,hi) across two packs.
__device__ __forceinline__ void apply_pair(v2f& LR, v2f& LI, v2f& HR, v2f& HI,
                                           float g00r, float g00i, float g01r,
                                           float g01i, float g10r, float g10i,
                                           float g11r, float g11i) {
  const v2f a00r = dup(g00r), a00i = dup(g00i), n00i = dup(-g00i);
  const v2f a01r = dup(g01r), a01i = dup(g01i), n01i = dup(-g01i);
  const v2f a10r = dup(g10r), a10i = dup(g10i), n10i = dup(-g10i);
  const v2f a11r = dup(g11r), a11i = dup(g11i), n11i = dup(-g11i);
  v2f NLR = pkfma(n01i, HI, pkfma(a01r, HR, pkfma(n00i, LI, pkmul(a00r, LR))));
  v2f NLI = pkfma(a01i, HR, pkfma(a01r, HI, pkfma(a00i, LR, pkmul(a00r, LI))));
  v2f NHR = pkfma(n11i, HI, pkfma(a11r, HR, pkfma(n10i, LI, pkmul(a10r, LR))));
  v2f NHI = pkfma(a11i, HR, pkfma(a11r, HI, pkfma(a10i, LR, pkmul(a10r, LI))));
  LR = NLR; LI = NLI; HR = NHR; HI = NHI;
}

__device__ __forceinline__ void crx_pairv(v2f& LR, v2f& LI, v2f& HR, v2f& HI,
                                          v2f cCC, v2f cSS, v2f cSSN) {
  v2f NLR = pkfma(cSS, HI, pkmul(cCC, LR));
  v2f NLI = pkfma(cSSN, HR, pkmul(cCC, LI));
  v2f NHR = pkfma(cSS, LI, pkmul(cCC, HR));
  v2f NHI = pkfma(cSSN, LR, pkmul(cCC, HI));
  LR = NLR; LI = NLI; HR = NHR; HI = NHI;
}

// U = RZ@RY on a lane bit (fully packed).
template <int RL, int VL>
__device__ __forceinline__ void u_lane(v2f (&CR)[4], v2f (&CI)[4], int l,
                                       float uAr, float uBi, float uAip,
                                       float uBrp) {
  const bool hi = (__popc(l & RL) & 1) != 0;
  const float Ai = hi ? uAip : -uAip;
  const float Br = hi ? uBrp : -uBrp;
  const v2f cAr = dup(uAr), cAi = dup(Ai), cAiN = dup(-Ai);
  const v2f cBr = dup(Br), cBi = dup(uBi), cBiN = dup(-uBi);
  v2f PR[4], PI[4];
#pragma unroll
  for (int q = 0; q < 4; ++q) { PR[q] = shf2<VL>(CR[q]); PI[q] = shf2<VL>(CI[q]); }
#pragma unroll
  for (int q = 0; q < 4; ++q) {
    v2f NR = pkfma(cBiN, PI[q], pkfma(cBr, PR[q], pkfma(cAiN, CI[q], pkmul(cAr, CR[q]))));
    v2f NI = pkfma(cBi, PR[q], pkfma(cBr, PI[q], pkfma(cAi, CR[q], pkmul(cAr, CI[q]))));
    CR[q] = NR; CI[q] = NI;
  }
}

// generic 2x2 gate on the PACK axis via op_sel (8 pk per pack).
__device__ __forceinline__ void gate_pack(v2f (&CR)[4], v2f (&CI)[4],
                                          v2f cA, v2f cB, v2f cBn,
                                          v2f cC, v2f cD, v2f cDn) {
#pragma unroll
  for (int q = 0; q < 4; ++q) {
    v2f NR = pkfma_hi1(cDn, CI[q], pkfma_hi1(cC, CR[q],
             pkfma_lo1(cBn, CI[q], pkmul_lo1(cA, CR[q]))));
    v2f NI = pkfma_hi1(cD, CR[q], pkfma_hi1(cC, CI[q],
             pkfma_lo1(cB, CR[q], pkmul_lo1(cA, CI[q]))));
    CR[q] = NR; CI[q] = NI;
  }
}

__device__ __forceinline__ void u_reg4(v2f (&CR)[4], v2f (&CI)[4], float uAr,
                                       float uBi, float uAip, float uBrp) {
  gate_pack(CR, CI,
            (v2f){uAr, uBrp}, (v2f){-uAip, uBi}, (v2f){uAip, -uBi},
            (v2f){-uBrp, uAr}, (v2f){uBi, uAip}, (v2f){-uBi, -uAip});
}

__device__ __forceinline__ void u3_reg4(v2f (&CR)[4], v2f (&CI)[4], const G1& g) {
  gate_pack(CR, CI,
            (v2f){g.r00, g.r10}, (v2f){g.i00, g.i10}, (v2f){-g.i00, -g.i10},
            (v2f){g.r01, g.r11}, (v2f){g.i01, g.i11}, (v2f){-g.i01, -g.i11});
}

// FUSED ring permutation: cnot_lr4<RL> (conditional .x/.y swap) followed by
// cnot_swap42 (.y of q0<->q2, q1<->q3), composed into one 16-cndmask step.
//  c=0: out[q] = (in[q].x, in[q^2].y)
//  c=1: out[q] = (in[q].y, in[q^2].x)
template <int RL>
__device__ __forceinline__ void ring_perm(v2f (&CR)[4], v2f (&CI)[4], int l) {
  const bool c = (__popc(l & RL) & 1) != 0;
  v2f nr[4], ni[4];
#pragma unroll
  for (int q = 0; q < 4; ++q) {
    const int p = q ^ 2;
    nr[q] = (v2f){c ? CR[q].y : CR[q].x, c ? CR[p].x : CR[p].y};
    ni[q] = (v2f){c ? CI[q].y : CI[q].x, c ? CI[p].x : CI[p].y};
  }
#pragma unroll
  for (int q = 0; q < 4; ++q) { CR[q] = nr[q]; CI[q] = ni[q]; }
}

__device__ __forceinline__ void cnot_swap21(v2f (&CR)[4], v2f (&CI)[4]) {
  v2f t;
  t = CR[2]; CR[2] = CR[3]; CR[3] = t;
  t = CI[2]; CI[2] = CI[3]; CI[3] = t;
}

template <int VL>
__device__ __forceinline__ void cnot_rl(v2f (&CR)[4], v2f (&CI)[4]) {
  CR[1] = shf2<VL>(CR[1]); CI[1] = shf2<VL>(CI[1]);
  CR[3] = shf2<VL>(CR[3]); CI[3] = shf2<VL>(CI[3]);
}

template <int RL, int VL>
__device__ __forceinline__ void crx_ll(v2f (&CR)[4], v2f (&CI)[4], int l,
                                       float co, float si) {
  const bool c = (__popc(l & RL) & 1) != 0;
  const float cc = c ? co : 1.f, ss = c ? si : 0.f;
  const v2f cCC = dup(cc), cSS = dup(ss), cSSN = dup(-ss);
  v2f PR[4], PI[4];
#pragma unroll
  for (int q = 0; q < 4; ++q) { PR[q] = shf2<VL>(CR[q]); PI[q] = shf2<VL>(CI[q]); }
#pragma unroll
  for (int q = 0; q < 4; ++q) {
    CR[q] = pkfma(cSS, PI[q], pkmul(cCC, CR[q]));
    CI[q] = pkfma(cSSN, PR[q], pkmul(cCC, CI[q]));
  }
}

template <int RL>
__device__ __forceinline__ void crx_lr4(v2f (&CR)[4], v2f (&CI)[4], int l,
                                        float co, float si) {
  const bool c = (__popc(l & RL) & 1) != 0;
  const float cc = c ? co : 1.f, ss = c ? si : 0.f;
  const v2f cc2 = dup(cc), ss2 = dup(ss), ssN2 = dup(-ss);
#pragma unroll
  for (int q = 0; q < 4; ++q) {
    v2f NR = pkfma_sw1(ss2, CI[q], pkmul(cc2, CR[q]));
    v2f NI = pkfma_sw1(ssN2, CR[q], pkmul(cc2, CI[q]));
    CR[q] = NR; CI[q] = NI;
  }
}

template <int RL, int VL>
__device__ __forceinline__ void u3_lane(v2f (&CR)[4], v2f (&CI)[4], int l,
                                        const G1& g) {
  const bool hi = (__popc(l & RL) & 1) != 0;
  const float Ar = hi ? g.r11 : g.r00, Aii = hi ? g.i11 : g.i00;
  const float Br = hi ? g.r10 : g.r01, Bi = hi ? g.i10 : g.i01;
  const v2f cAr = dup(Ar), cAi = dup(Aii), cAiN = dup(-Aii);
  const v2f cBr = dup(Br), cBi = dup(Bi), cBiN = dup(-Bi);
  v2f PR[4], PI[4];
#pragma unroll
  for (int q = 0; q < 4; ++q) { PR[q] = shf2<VL>(CR[q]); PI[q] = shf2<VL>(CI[q]); }
#pragma unroll
  for (int q = 0; q < 4; ++q) {
    v2f NR = pkfma(cBiN, PI[q], pkfma(cBr, PR[q], pkfma(cAiN, CI[q], pkmul(cAr, CR[q]))));
    v2f NI = pkfma(cBi, PR[q], pkfma(cBr, PI[q], pkfma(cAi, CR[q], pkmul(cAr, CI[q]))));
    CR[q] = NR; CI[q] = NI;
  }
}

__device__ __forceinline__ G1 load_g1(const float* __restrict__ cs, int k) {
  const float* p = cs + 22 + 8 * k;
  G1 g;
  g.r00 = p[0]; g.i00 = p[1]; g.r01 = p[2]; g.i01 = p[3];
  g.r10 = p[4]; g.i10 = p[5]; g.r11 = p[6]; g.i11 = p[7];
  return g;
}

// ---- prep: batch-invariant coefficients -> d_ws ----
struct Cx { float r, i; };
__device__ __forceinline__ Cx cmul(Cx a, Cx b) {
  return {a.r * b.r - a.i * b.i, a.r * b.i + a.i * b.r};
}
__device__ __forceinline__ Cx cconj(Cx a) { return {a.r, -a.i}; }
__device__ __forceinline__ Cx cadd(Cx a, Cx b) { return {a.r + b.r, a.i + b.i}; }
__device__ __forceinline__ Cx csub(Cx a, Cx b) { return {a.r - b.r, a.i - b.i}; }
__device__ __forceinline__ Cx cscale(float s, Cx a) { return {s * a.r, s * a.i}; }

__device__ void congr(float n00, Cx n01, float n11, Cx G00, Cx G01, Cx G10,
                      Cx G11, float& m00, Cx& m01, float& m11) {
  Cx t0 = cadd(cscale(n00, G00), cmul(n01, G10));
  Cx t1 = cadd(cmul(cconj(n01), G00), cscale(n11, G10));
  Cx u0 = cadd(cscale(n00, G01), cmul(n01, G11));
  Cx u1 = cadd(cmul(cconj(n01), G01), cscale(n11, G11));
  m00 = cadd(cmul(cconj(G00), t0), cmul(cconj(G10), t1)).r;
  m01 = cadd(cmul(cconj(G00), u0), cmul(cconj(G10), u1));
  m11 = cadd(cmul(cconj(G01), u0), cmul(cconj(G11), u1)).r;
}

__device__ void build_u3(float t, float p, float l, Cx& G00, Cx& G01, Cx& G10,
                         Cx& G11) {
  float st, ct, sp, cp, sl, cl;
  sincosf(0.5f * t, &st, &ct);
  sincosf(p, &sp, &cp);
  sincosf(l, &sl, &cl);
  G00 = {ct, 0.f};
  G01 = {-cl * st, -sl * st};
  G10 = {cp * st, sp * st};
  G11 = {(cp * cl - sp * sl) * ct, (sp * cl + cp * sl) * ct};
}

__global__ void prep_kernel(const float* __restrict__ crx,
                            const float* __restrict__ u3p,
                            float* __restrict__ ws) {
  const int t = threadIdx.x;
  if (t < 11) {
    float s, c;
    sincosf(0.5f * crx[t], &s, &c);
    ws[2 * t] = c; ws[2 * t + 1] = s;
  } else if (t >= 16 && t < 23) {
    const int k = t - 16;
    float st, ct, sp, cp, sl, cl;
    sincosf(0.5f * u3p[3 * k], &st, &ct);
    sincosf(u3p[3 * k + 1], &sp, &cp);
    sincosf(u3p[3 * k + 2], &sl, &cl);
    float* o = ws + 22 + 8 * k;
    o[0] = ct;            o[1] = 0.f;
    o[2] = -cl * st;      o[3] = -sl * st;
    o[4] = cp * st;       o[5] = sp * st;
    o[6] = (cp * cl - sp * sl) * ct;
    o[7] = (sp * cl + cp * sl) * ct;
  } else if (t == 30) {
    // folded measurement matrices (u3#5, crx10, u3#6, Z7)
    Cx A00, A01, A10, A11, C00, C01, C10, C11;
    build_u3(u3p[15], u3p[16], u3p[17], A00, A01, A10, A11);  // u3 gate 5
    build_u3(u3p[18], u3p[19], u3p[20], C00, C01, C10, C11);  // u3 gate 6
    float n00 = (C00.r * C00.r + C00.i * C00.i) - (C10.r * C10.r + C10.i * C10.i);
    Cx n01 = csub(cmul(cconj(C00), C01), cmul(cconj(C10), C11));
    float n11 = (C01.r * C01.r + C01.i * C01.i) - (C11.r * C11.r + C11.i * C11.i);
    float m00, m11; Cx m01;
    congr(n00, n01, n11, A00, A01, A10, A11, m00, m01, m11);
    ws[80] = m00; ws[81] = m11; ws[82] = 2.f * m01.r; ws[83] = -2.f * m01.i;
    float co, si;
    sincosf(0.5f * crx[10], &si, &co);
    Cx R00 = {co, 0.f}, R01 = {0.f, -si}, R10 = {0.f, -si}, R11 = {co, 0.f};
    float p00, p11; Cx p01;
    congr(n00, n01, n11, R00, R01, R10, R11, p00, p01, p11);
    congr(p00, p01, p11, A00, A01, A10, A11, m00, m01, m11);
    ws[84] = m00; ws[85] = m11; ws[86] = 2.f * m01.r; ws[87] = -2.f * m01.i;
  }
}

__global__ __launch_bounds__(256, 4) void qcnn_kernel(
    const float* __restrict__ theta, const float* __restrict__ phi,
    const float* __restrict__ cs, float* __restrict__ out, int nbatch) {
  const int tid = blockIdx.x * blockDim.x + threadIdx.x;
  const int wave = tid >> 6;
  const int lane = threadIdx.x & 63;
  const int l = lane & 31;
  int b = wave * 2 + (lane >> 5);
  if (b >= nbatch) b = nbatch - 1;

  float sth, cth, sph, cph;
  __sincosf(0.5f * theta[b], &sth, &cth);
  __sincosf(0.5f * phi[b], &sph, &cph);
  const float uAr = cph * cth, uBi = sph * sth;
  const float uAip = sph * cth, uBrp = cph * sth;

  // ---- cycle-1 closed form: amp(x) = g0^(8-k) g1^k, k = popc(x) ----
  const float g0r = uAr, g0i = -uAip, g1r = uBrp, g1i = uBi;
  float Zr = (l & 16) ? g1r : g0r, Zi = (l & 16) ? g1i : g0i;
#define MULBIT(m)                                                     \
  {                                                                   \
    const float Fr = (l & m) ? g1r : g0r, Fi = (l & m) ? g1i : g0i;   \
    const float nr = Zr * Fr - Zi * Fi, ni = Zr * Fi + Zi * Fr;       \
    Zr = nr; Zi = ni;                                                 \
  }
  MULBIT(8) MULBIT(4) MULBIT(2) MULBIT(1)
#undef MULBIT
  const float g00r = g0r * g0r - g0i * g0i, g00i = 2.f * g0r * g0i;
  const float g11r = g1r * g1r - g1i * g1i, g11i = 2.f * g1r * g1i;
  const float h0r = g00r * g0r - g00i * g0i, h0i = g00r * g0i + g00i * g0r;
  const float h1r = g00r * g1r - g00i * g1i, h1i = g00r * g1i + g00i * g1r;
  const float h2r = g11r * g0r - g11i * g0i, h2i = g11r * g0i + g11i * g0r;
  const float h3r = g11r * g1r - g11i * g1i, h3i = g11r * g1i + g11i * g1r;

  v2f CR[4], CI[4];
  {
    const v2f Zrv = dup(Zr), Ziv = dup(Zi), ZivN = dup(-Zi);
    const v2f Hr[4] = {{h0r, h1r}, {h1r, h2r}, {h1r, h2r}, {h2r, h3r}};
    const v2f Hi[4] = {{h0i, h1i}, {h1i, h2i}, {h1i, h2i}, {h2i, h3i}};
#pragma unroll
    for (int q = 0; q < 4; ++q) {
      CR[q] = pkfma(ZivN, Hi[q], pkmul(Zrv, Hr[q]));
      CI[q] = pkfma(Ziv, Hr[q], pkmul(Zrv, Hi[q]));
    }
  }

#define ULANE(RL, VL) u_lane<RL, VL>(CR, CI, l, uAr, uBi, uAip, uBrp)
#define UREGS() do { u_reg4(CR, CI, uAr, uBi, uAip, uBrp); \
                     apply_pair(CR[0], CI[0], CR[2], CI[2], uAr, -uAip, \
                                -uBrp, uBi, uBrp, uBi, uAr, uAip); \
                     apply_pair(CR[1], CI[1], CR[3], CI[3], uAr, -uAip, \
                                -uBrp, uBi, uBrp, uBi, uAr, uAip); \
                     apply_pair(CR[0], CI[0], CR[1], CI[1], uAr, -uAip, \
                                -uBrp, uBi, uBrp, uBi, uAr, uAip); \
                     apply_pair(CR[2], CI[2], CR[3], CI[3], uAr, -uAip, \
                                -uBrp, uBi, uBrp, uBi, uAr, uAip); } while (0)
#define RING(RL45, VL70) do { ring_perm<RL45>(CR, CI, l); \
                              cnot_swap21(CR, CI); \
                              cnot_rl<VL70>(CR, CI); } while (0)

  // cycle 1 ring (U part replaced by closed form above)
  RING(31, 24);
  // cycle 2
  ULANE(16, 24); ULANE(24, 12); ULANE(28, 6);  ULANE(30, 3); ULANE(31, 1);
  UREGS(); RING(21, 20);
  // cycle 3
  ULANE(16, 20); ULANE(8, 10);  ULANE(20, 5);  ULANE(10, 2); ULANE(21, 1);
  UREGS(); RING(19, 30);
  // cycle 4
  ULANE(16, 30); ULANE(24, 15); ULANE(12, 7);  ULANE(6, 3);  ULANE(19, 1);
  UREGS(); RING(17, 17);
#undef RING
#undef UREGS
#undef ULANE

  // ---- QCNN section ----
#define LD(k) const float co##k = cs[2 * k], si##k = cs[2 * k + 1]
  LD(0); crx_ll<16, 8>(CR, CI, l, co0, si0);   // (0,1)
  LD(1); crx_ll<4, 2>(CR, CI, l, co1, si1);    // (2,3)
  LD(2); crx_lr4<17>(CR, CI, l, co2, si2);     // (4,5) pack-target
  LD(3);                                       // (6,7): ctrl bit1, tgt bit0
  crx_pairv(CR[2], CI[2], CR[3], CI[3], dup(co3), dup(si3), dup(-si3));
  LD(4); crx_ll<8, 4>(CR, CI, l, co4, si4);    // (1,2)
  LD(5); crx_ll<2, 1>(CR, CI, l, co5, si5);    // (3,4)
  LD(6);                                       // (5,6): ctrl pack -> half coeffs
  {
    const v2f cCC = (v2f){1.f, co6}, cSS = (v2f){0.f, si6}, cSSN = (v2f){0.f, -si6};
    crx_pairv(CR[0], CI[0], CR[2], CI[2], cCC, cSS, cSSN);
    crx_pairv(CR[1], CI[1], CR[3], CI[3], cCC, cSS, cSSN);
  }

  { G1 g = load_g1(cs, 0); u3_lane<8, 8>(CR, CI, l, g); }  // wire 1
  { G1 g = load_g1(cs, 1); u3_lane<2, 2>(CR, CI, l, g); }  // wire 3
  { G1 g = load_g1(cs, 2); u3_reg4(CR, CI, g); }           // wire 5 pack
  { G1 g = load_g1(cs, 3);                                 // wire 7 (bit0)
    apply_pair(CR[0], CI[0], CR[1], CI[1], g.r00, g.i00, g.r01, g.i01,
               g.r10, g.i10, g.r11, g.i11);
    apply_pair(CR[2], CI[2], CR[3], CI[3], g.r00, g.i00, g.r01, g.i01,
               g.r10, g.i10, g.r11, g.i11); }

  LD(7); crx_ll<8, 2>(CR, CI, l, co7, si7);    // (1,3)
  LD(8);                                       // (5,7): ctrl pack, tgt bit0
  {
    const v2f cCC = (v2f){1.f, co8}, cSS = (v2f){0.f, si8}, cSSN = (v2f){0.f, -si8};
    crx_pairv(CR[0], CI[0], CR[1], CI[1], cCC, cSS, cSSN);
    crx_pairv(CR[2], CI[2], CR[3], CI[3], cCC, cSS, cSSN);
  }
  LD(9); crx_lr4<2>(CR, CI, l, co9, si9);      // (3,5) pack-target

  { G1 g = load_g1(cs, 4); u3_lane<2, 2>(CR, CI, l, g); }  // wire 3
#undef LD

  // ---- folded measurement: ev = s^H M_c s, c = parity(l&2) ----
  {
    const bool cH = (l & 2) != 0;
    const float w00 = cH ? cs[84] : cs[80];
    const float w11 = cH ? cs[85] : cs[81];
    const float wa  = cH ? cs[86] : cs[82];
    const float wb  = cH ? cs[87] : cs[83];
    v2f PL = pkfma(CI[0], CI[0], pkmul(CR[0], CR[0]));
    PL = PL + pkfma(CI[2], CI[2], pkmul(CR[2], CR[2]));
    v2f PH = pkfma(CI[1], CI[1], pkmul(CR[1], CR[1]));
    PH = PH + pkfma(CI[3], CI[3], pkmul(CR[3], CR[3]));
    v2f X = pkfma(CI[0], CI[1], pkmul(CR[0], CR[1]));
    X = X + pkfma(CI[2], CI[3], pkmul(CR[2], CR[3]));
    v2f Y = pkmul(CR[0], CI[1]) - pkmul(CI[0], CR[1]);
    Y = Y + (pkmul(CR[2], CI[3]) - pkmul(CI[2], CR[3]));
    v2f EV = pkfma(dup(wb), Y, pkfma(dup(wa), X,
             pkfma(dup(w11), PH, pkmul(dup(w00), PL))));
    float v = EV.x + EV.y;
    v += shxm<1>(v); v += shxm<2>(v); v += shxm<4>(v);
    v += shxm<8>(v); v += shxm<16>(v);
    if (l == 0) out[b] = fmaxf(v, 0.f);
  }
}

extern "C" void kernel_launch(void* const* d_in, const int* in_sizes, int n_in,
                              void* d_out, int out_size, void* d_ws, size_t ws_size,
                              hipStream_t stream) {
  const float* theta = (const float*)d_in[0];
  const float* phi = (const float*)d_in[1];
  const float* crx = (const float*)d_in[2];
  const float* u3p = (const float*)d_in[3];
  float* out = (float*)d_out;
  float* ws = (float*)d_ws;
  const int nb = in_sizes[0];

  prep_kernel<<<1, 64, 0, stream>>>(crx, u3p, ws);

  const int elems_per_block = 8;  // 4 waves * 2 elements
  dim3 block(256);
  dim3 grid((nb + elems_per_block - 1) / elems_per_block);
  qcnn_kernel<<<grid, block, 0, stream>>>(theta, phi, ws, out, nb);
}

// Round 11
// 76.476 us; speedup vs baseline: 1.0117x; 1.0117x over previous
//
#include <hip/hip_runtime.h>
#include <math.h>

// Base = round-9 kernel (best: 75.27 us total), with ONE isolated change
// kept from r10: the fused ring permutation (ring_perm).  Shuffles are
// reverted to the r9 DPP/ds_swizzle mix (r10's all-ds_swizzle regressed
// 75.27 -> 77.37: DS latency not hidden at 4 waves/SIMD; DPP forwards).
//
// Layout: 8 complex amps/lane, 2 batch elements/wave64 (one per 32-lane
// half).  Amp p = l<<3 | r, l = lane&31 (5 lane bits, wires 0..4), r = reg
// (3 bits: bit2=wire5=pack axis, bit1=wire6, bit0=wire7).  Regs packed as
// float2 along reg bit2.  asm v_pk_* math; prep kernel for batch-invariant
// coeffs; cycle-1 closed-form product state; folded measurement
// (u3#5, crx10, u3#6, Z7 -> two 2x2 Hermitian forms).
//
// Lane-bit lazy GF(2) CNOT relabeling (validated r4..r9):
//  C2 U:(16,24)(24,12)(28,6)(30,3)(31,1) lr-ctrl 21  rl-V 20
//  C3 U:(16,20)(8,10)(20,5)(10,2)(21,1)  lr-ctrl 19  rl-V 30
//  C4 U:(16,30)(24,15)(12,7)(6,3)(19,1)  lr-ctrl 17  rl-V 17
//  QCNN: w0(16,17) w1(8,8) w2(4,4) w3(2,2) w4(17,1); reg wires 5,6,7=bits 2,1,0.

typedef float v2f __attribute__((ext_vector_type(2)));

__device__ __forceinline__ v2f pkmul(v2f a, v2f b) {
  v2f d; asm("v_pk_mul_f32 %0, %1, %2" : "=v"(d) : "v"(a), "v"(b)); return d;
}
__device__ __forceinline__ v2f pkfma(v2f a, v2f b, v2f c) {
  v2f d; asm("v_pk_fma_f32 %0, %1, %2, %3" : "=v"(d) : "v"(a), "v"(b), "v"(c)); return d;
}
__device__ __forceinline__ v2f pkmul_lo1(v2f a, v2f b) {
  v2f d; asm("v_pk_mul_f32 %0, %1, %2 op_sel:[0,0] op_sel_hi:[1,0]"
             : "=v"(d) : "v"(a), "v"(b)); return d;
}
__device__ __forceinline__ v2f pkfma_lo1(v2f a, v2f b, v2f c) {
  v2f d; asm("v_pk_fma_f32 %0, %1, %2, %3 op_sel:[0,0,0] op_sel_hi:[1,0,1]"
             : "=v"(d) : "v"(a), "v"(b), "v"(c)); return d;
}
__device__ __forceinline__ v2f pkfma_hi1(v2f a, v2f b, v2f c) {
  v2f d; asm("v_pk_fma_f32 %0, %1, %2, %3 op_sel:[0,1,0] op_sel_hi:[1,1,1]"
             : "=v"(d) : "v"(a), "v"(b), "v"(c)); return d;
}
__device__ __forceinline__ v2f pkfma_sw1(v2f a, v2f b, v2f c) {
  v2f d; asm("v_pk_fma_f32 %0, %1, %2, %3 op_sel:[0,1,0] op_sel_hi:[1,0,1]"
             : "=v"(d) : "v"(a), "v"(b), "v"(c)); return d;
}
__device__ __forceinline__ v2f dup(float x) { return (v2f){x, x}; }

// r9 shuffle mix: DPP for masks {1,2,3,7,8,15} (VALU, forwarded),
// ds_swizzle otherwise (all masks < 32 in this layout).
template <int M>
__device__ __forceinline__ float shxm(float v) {
  if constexpr (M == 1 || M == 2 || M == 3 || M == 7 || M == 8 || M == 15) {
    constexpr int ctrl = (M == 1) ? 0xB1 : (M == 2) ? 0x4E : (M == 3) ? 0x1B
                         : (M == 7) ? 0x141 : (M == 8) ? 0x128 : 0x140;
    return __int_as_float(__builtin_amdgcn_update_dpp(
        0, __float_as_int(v), ctrl, 0xF, 0xF, true));
  } else {
    return __int_as_float(__builtin_amdgcn_ds_swizzle(
        __float_as_int(v), (M << 10) | 0x1F));
  }
}
template <int M>
__device__ __forceinline__ v2f shf2(v2f a) {
  return (v2f){shxm<M>(a.x), shxm<M>(a.y)};
}

struct G1 { float r00, i00, r01, i01, r10, i10, r11, i11; };

// generic 2x2 complex gate on a reg pair (lo,hi) across two packs.
__device__ __forceinline__ void apply_pair(v2f& LR, v2f& LI, v2f& HR, v2f& HI,
                                           float g00r, float g00i, float g01r,
                                           float g01i, float g10r, float g10i,
                                           float g11r, float g11i) {
  const v2f a00r = dup(g00r), a00i = dup(g00i), n00i = dup(-g00i);
  const v2f a01r = dup(g01r), a01i = dup(g01i), n01i = dup(-g01i);
  const v2f a10r = dup(g10r), a10i = dup(g10i), n10i = dup(-g10i);
  const v2f a11r = dup(g11r), a11i = dup(g11i), n11i = dup(-g11i);
  v2f NLR = pkfma(n01i, HI, pkfma(a01r, HR, pkfma(n00i, LI, pkmul(a00r, LR))));
  v2f NLI = pkfma(a01i, HR, pkfma(a01r, HI, pkfma(a00i, LR, pkmul(a00r, LI))));
  v2f NHR = pkfma(n11i, HI, pkfma(a11r, HR, pkfma(n10i, LI, pkmul(a10r, LR))));
  v2f NHI = pkfma(a11i, HR, pkfma(a11r, HI, pkfma(a10i, LR, pkmul(a10r, LI))));
  LR = NLR; LI = NLI; HR = NHR; HI = NHI;
}

__device__ __forceinline__ void crx_pairv(v2f& LR, v2f& LI, v2f& HR, v2f& HI,
                                          v2f cCC, v2f cSS, v2f cSSN) {
  v2f NLR = pkfma(cSS, HI, pkmul(cCC, LR));
  v2f NLI = pkfma(cSSN, HR, pkmul(cCC, LI));
  v2f NHR = pkfma(cSS, LI, pkmul(cCC, HR));
  v2f NHI = pkfma(cSSN, LR, pkmul(cCC, HI));
  LR = NLR; LI = NLI; HR = NHR; HI = NHI;
}

// U = RZ@RY on a lane bit (fully packed).
template <int RL, int VL>
__device__ __forceinline__ void u_lane(v2f (&CR)[4], v2f (&CI)[4], int l,
                                       float uAr, float uBi, float uAip,
                                       float uBrp) {
  const bool hi = (__popc(l & RL) & 1) != 0;
  const float Ai = hi ? uAip : -uAip;
  const float Br = hi ? uBrp : -uBrp;
  const v2f cAr = dup(uAr), cAi = dup(Ai), cAiN = dup(-Ai);
  const v2f cBr = dup(Br), cBi = dup(uBi), cBiN = dup(-uBi);
  v2f PR[4], PI[4];
#pragma unroll
  for (int q = 0; q < 4; ++q) { PR[q] = shf2<VL>(CR[q]); PI[q] = shf2<VL>(CI[q]); }
#pragma unroll
  for (int q = 0; q < 4; ++q) {
    v2f NR = pkfma(cBiN, PI[q], pkfma(cBr, PR[q], pkfma(cAiN, CI[q], pkmul(cAr, CR[q]))));
    v2f NI = pkfma(cBi, PR[q], pkfma(cBr, PI[q], pkfma(cAi, CR[q], pkmul(cAr, CI[q]))));
    CR[q] = NR; CI[q] = NI;
  }
}

// generic 2x2 gate on the PACK axis via op_sel (8 pk per pack).
__device__ __forceinline__ void gate_pack(v2f (&CR)[4], v2f (&CI)[4],
                                          v2f cA, v2f cB, v2f cBn,
                                          v2f cC, v2f cD, v2f cDn) {
#pragma unroll
  for (int q = 0; q < 4; ++q) {
    v2f NR = pkfma_hi1(cDn, CI[q], pkfma_hi1(cC, CR[q],
             pkfma_lo1(cBn, CI[q], pkmul_lo1(cA, CR[q]))));
    v2f NI = pkfma_hi1(cD, CR[q], pkfma_hi1(cC, CI[q],
             pkfma_lo1(cB, CR[q], pkmul_lo1(cA, CI[q]))));
    CR[q] = NR; CI[q] = NI;
  }
}

__device__ __forceinline__ void u_reg4(v2f (&CR)[4], v2f (&CI)[4], float uAr,
                                       float uBi, float uAip, float uBrp) {
  gate_pack(CR, CI,
            (v2f){uAr, uBrp}, (v2f){-uAip, uBi}, (v2f){uAip, -uBi},
            (v2f){-uBrp, uAr}, (v2f){uBi, uAip}, (v2f){-uBi, -uAip});
}

__device__ __forceinline__ void u3_reg4(v2f (&CR)[4], v2f (&CI)[4], const G1& g) {
  gate_pack(CR, CI,
            (v2f){g.r00, g.r10}, (v2f){g.i00, g.i10}, (v2f){-g.i00, -g.i10},
            (v2f){g.r01, g.r11}, (v2f){g.i01, g.i11}, (v2f){-g.i01, -g.i11});
}

// FUSED ring permutation: cnot_lr4<RL> (conditional .x/.y swap) followed by
// cnot_swap42 (.y of q0<->q2, q1<->q3), composed into one 16-cndmask step.
//  c=0: out[q] = (in[q].x, in[q^2].y)
//  c=1: out[q] = (in[q].y, in[q^2].x)
template <int RL>
__device__ __forceinline__ void ring_perm(v2f (&CR)[4], v2f (&CI)[4], int l) {
  const bool c = (__popc(l & RL) & 1) != 0;
  v2f nr[4], ni[4];
#pragma unroll
  for (int q = 0; q < 4; ++q) {
    const int p = q ^ 2;
    nr[q] = (v2f){c ? CR[q].y : CR[q].x, c ? CR[p].x : CR[p].y};
    ni[q] = (v2f){c ? CI[q].y : CI[q].x, c ? CI[p].x : CI[p].y};
  }
#pragma unroll
  for (int q = 0; q < 4; ++q) { CR[q] = nr[q]; CI[q] = ni[q]; }
}

__device__ __forceinline__ void cnot_swap21(v2f (&CR)[4], v2f (&CI)[4]) {
  v2f t;
  t = CR[2]; CR[2] = CR[3]; CR[3] = t;
  t = CI[2]; CI[2] = CI[3]; CI[3] = t;
}

template <int VL>
__device__ __forceinline__ void cnot_rl(v2f (&CR)[4], v2f (&CI)[4]) {
  CR[1] = shf2<VL>(CR[1]); CI[1] = shf2<VL>(CI[1]);
  CR[3] = shf2<VL>(CR[3]); CI[3] = shf2<VL>(CI[3]);
}

template <int RL, int VL>
__device__ __forceinline__ void crx_ll(v2f (&CR)[4], v2f (&CI)[4], int l,
                                       float co, float si) {
  const bool c = (__popc(l & RL) & 1) != 0;
  const float cc = c ? co : 1.f, ss = c ? si : 0.f;
  const v2f cCC = dup(cc), cSS = dup(ss), cSSN = dup(-ss);
  v2f PR[4], PI[4];
#pragma unroll
  for (int q = 0; q < 4; ++q) { PR[q] = shf2<VL>(CR[q]); PI[q] = shf2<VL>(CI[q]); }
#pragma unroll
  for (int q = 0; q < 4; ++q) {
    CR[q] = pkfma(cSS, PI[q], pkmul(cCC, CR[q]));
    CI[q] = pkfma(cSSN, PR[q], pkmul(cCC, CI[q]));
  }
}

template <int RL>
__device__ __forceinline__ void crx_lr4(v2f (&CR)[4], v2f (&CI)[4], int l,
                                        float co, float si) {
  const bool c = (__popc(l & RL) & 1) != 0;
  const float cc = c ? co : 1.f, ss = c ? si : 0.f;
  const v2f cc2 = dup(cc), ss2 = dup(ss), ssN2 = dup(-ss);
#pragma unroll
  for (int q = 0; q < 4; ++q) {
    v2f NR = pkfma_sw1(ss2, CI[q], pkmul(cc2, CR[q]));
    v2f NI = pkfma_sw1(ssN2, CR[q], pkmul(cc2, CI[q]));
    CR[q] = NR; CI[q] = NI;
  }
}

template <int RL, int VL>
__device__ __forceinline__ void u3_lane(v2f (&CR)[4], v2f (&CI)[4], int l,
                                        const G1& g) {
  const bool hi = (__popc(l & RL) & 1) != 0;
  const float Ar = hi ? g.r11 : g.r00, Aii = hi ? g.i11 : g.i00;
  const float Br = hi ? g.r10 : g.r01, Bi = hi ? g.i10 : g.i01;
  const v2f cAr = dup(Ar), cAi = dup(Aii), cAiN = dup(-Aii);
  const v2f cBr = dup(Br), cBi = dup(Bi), cBiN = dup(-Bi);
  v2f PR[4], PI[4];
#pragma unroll
  for (int q = 0; q < 4; ++q) { PR[q] = shf2<VL>(CR[q]); PI[q] = shf2<VL>(CI[q]); }
#pragma unroll
  for (int q = 0; q < 4; ++q) {
    v2f NR = pkfma(cBiN, PI[q], pkfma(cBr, PR[q], pkfma(cAiN, CI[q], pkmul(cAr, CR[q]))));
    v2f NI = pkfma(cBi, PR[q], pkfma(cBr, PI[q], pkfma(cAi, CR[q], pkmul(cAr, CI[q]))));
    CR[q] = NR; CI[q] = NI;
  }
}

__device__ __forceinline__ G1 load_g1(const float* __restrict__ cs, int k) {
  const float* p = cs + 22 + 8 * k;
  G1 g;
  g.r00 = p[0]; g.i00 = p[1]; g.r01 = p[2]; g.i01 = p[3];
  g.r10 = p[4]; g.i10 = p[5]; g.r11 = p[6]; g.i11 = p[7];
  return g;
}

// ---- prep: batch-invariant coefficients -> d_ws ----
struct Cx { float r, i; };
__device__ __forceinline__ Cx cmul(Cx a, Cx b) {
  return {a.r * b.r - a.i * b.i, a.r * b.i + a.i * b.r};
}
__device__ __forceinline__ Cx cconj(Cx a) { return {a.r, -a.i}; }
__device__ __forceinline__ Cx cadd(Cx a, Cx b) { return {a.r + b.r, a.i + b.i}; }
__device__ __forceinline__ Cx csub(Cx a, Cx b) { return {a.r - b.r, a.i - b.i}; }
__device__ __forceinline__ Cx cscale(float s, Cx a) { return {s * a.r, s * a.i}; }

__device__ void congr(float n00, Cx n01, float n11, Cx G00, Cx G01, Cx G10,
                      Cx G11, float& m00, Cx& m01, float& m11) {
  Cx t0 = cadd(cscale(n00, G00), cmul(n01, G10));
  Cx t1 = cadd(cmul(cconj(n01), G00), cscale(n11, G10));
  Cx u0 = cadd(cscale(n00, G01), cmul(n01, G11));
  Cx u1 = cadd(cmul(cconj(n01), G01), cscale(n11, G11));
  m00 = cadd(cmul(cconj(G00), t0), cmul(cconj(G10), t1)).r;
  m01 = cadd(cmul(cconj(G00), u0), cmul(cconj(G10), u1));
  m11 = cadd(cmul(cconj(G01), u0), cmul(cconj(G11), u1)).r;
}

__device__ void build_u3(float t, float p, float l, Cx& G00, Cx& G01, Cx& G10,
                         Cx& G11) {
  float st, ct, sp, cp, sl, cl;
  sincosf(0.5f * t, &st, &ct);
  sincosf(p, &sp, &cp);
  sincosf(l, &sl, &cl);
  G00 = {ct, 0.f};
  G01 = {-cl * st, -sl * st};
  G10 = {cp * st, sp * st};
  G11 = {(cp * cl - sp * sl) * ct, (sp * cl + cp * sl) * ct};
}

__global__ void prep_kernel(const float* __restrict__ crx,
                            const float* __restrict__ u3p,
                            float* __restrict__ ws) {
  const int t = threadIdx.x;
  if (t < 11) {
    float s, c;
    sincosf(0.5f * crx[t], &s, &c);
    ws[2 * t] = c; ws[2 * t + 1] = s;
  } else if (t >= 16 && t < 23) {
    const int k = t - 16;
    float st, ct, sp, cp, sl, cl;
    sincosf(0.5f * u3p[3 * k], &st, &ct);
    sincosf(u3p[3 * k + 1], &sp, &cp);
    sincosf(u3p[3 * k + 2], &sl, &cl);
    float* o = ws + 22 + 8 * k;
    o[0] = ct;            o[1] = 0.f;
    o[2] = -cl * st;      o[3] = -sl * st;
    o[4] = cp * st;       o[5] = sp * st;
    o[6] = (cp * cl - sp * sl) * ct;
    o[7] = (sp * cl + cp * sl) * ct;
  } else if (t == 30) {
    // folded measurement matrices (u3#5, crx10, u3#6, Z7)
    Cx A00, A01, A10, A11, C00, C01, C10, C11;
    build_u3(u3p[15], u3p[16], u3p[17], A00, A01, A10, A11);  // u3 gate 5
    build_u3(u3p[18], u3p[19], u3p[20], C00, C01, C10, C11);  // u3 gate 6
    float n00 = (C00.r * C00.r + C00.i * C00.i) - (C10.r * C10.r + C10.i * C10.i);
    Cx n01 = csub(cmul(cconj(C00), C01), cmul(cconj(C10), C11));
    float n11 = (C01.r * C01.r + C01.i * C01.i) - (C11.r * C11.r + C11.i * C11.i);
    float m00, m11; Cx m01;
    congr(n00, n01, n11, A00, A01, A10, A11, m00, m01, m11);
    ws[80] = m00; ws[81] = m11; ws[82] = 2.f * m01.r; ws[83] = -2.f * m01.i;
    float co, si;
    sincosf(0.5f * crx[10], &si, &co);
    Cx R00 = {co, 0.f}, R01 = {0.f, -si}, R10 = {0.f, -si}, R11 = {co, 0.f};
    float p00, p11; Cx p01;
    congr(n00, n01, n11, R00, R01, R10, R11, p00, p01, p11);
    congr(p00, p01, p11, A00, A01, A10, A11, m00, m01, m11);
    ws[84] = m00; ws[85] = m11; ws[86] = 2.f * m01.r; ws[87] = -2.f * m01.i;
  }
}

__global__ __launch_bounds__(256, 4) void qcnn_kernel(
    const float* __restrict__ theta, const float* __restrict__ phi,
    const float* __restrict__ cs, float* __restrict__ out, int nbatch) {
  const int tid = blockIdx.x * blockDim.x + threadIdx.x;
  const int wave = tid >> 6;
  const int lane = threadIdx.x & 63;
  const int l = lane & 31;
  int b = wave * 2 + (lane >> 5);
  if (b >= nbatch) b = nbatch - 1;

  float sth, cth, sph, cph;
  __sincosf(0.5f * theta[b], &sth, &cth);
  __sincosf(0.5f * phi[b], &sph, &cph);
  const float uAr = cph * cth, uBi = sph * sth;
  const float uAip = sph * cth, uBrp = cph * sth;

  // ---- cycle-1 closed form: amp(x) = g0^(8-k) g1^k, k = popc(x) ----
  const float g0r = uAr, g0i = -uAip, g1r = uBrp, g1i = uBi;
  float Zr = (l & 16) ? g1r : g0r, Zi = (l & 16) ? g1i : g0i;
#define MULBIT(m)                                                     \
  {                                                                   \
    const float Fr = (l & m) ? g1r : g0r, Fi = (l & m) ? g1i : g0i;   \
    const float nr = Zr * Fr - Zi * Fi, ni = Zr * Fi + Zi * Fr;       \
    Zr = nr; Zi = ni;                                                 \
  }
  MULBIT(8) MULBIT(4) MULBIT(2) MULBIT(1)
#undef MULBIT
  const float g00r = g0r * g0r - g0i * g0i, g00i = 2.f * g0r * g0i;
  const float g11r = g1r * g1r - g1i * g1i, g11i = 2.f * g1r * g1i;
  const float h0r = g00r * g0r - g00i * g0i, h0i = g00r * g0i + g00i * g0r;
  const float h1r = g00r * g1r - g00i * g1i, h1i = g00r * g1i + g00i * g1r;
  const float h2r = g11r * g0r - g11i * g0i, h2i = g11r * g0i + g11i * g0r;
  const float h3r = g11r * g1r - g11i * g1i, h3i = g11r * g1i + g11i * g1r;

  v2f CR[4], CI[4];
  {
    const v2f Zrv = dup(Zr), Ziv = dup(Zi), ZivN = dup(-Zi);
    const v2f Hr[4] = {{h0r, h1r}, {h1r, h2r}, {h1r, h2r}, {h2r, h3r}};
    const v2f Hi[4] = {{h0i, h1i}, {h1i, h2i}, {h1i, h2i}, {h2i, h3i}};
#pragma unroll
    for (int q = 0; q < 4; ++q) {
      CR[q] = pkfma(ZivN, Hi[q], pkmul(Zrv, Hr[q]));
      CI[q] = pkfma(Ziv, Hr[q], pkmul(Zrv, Hi[q]));
    }
  }

#define ULANE(RL, VL) u_lane<RL, VL>(CR, CI, l, uAr, uBi, uAip, uBrp)
#define UREGS() do { u_reg4(CR, CI, uAr, uBi, uAip, uBrp); \
                     apply_pair(CR[0], CI[0], CR[2], CI[2], uAr, -uAip, \
                                -uBrp, uBi, uBrp, uBi, uAr, uAip); \
                     apply_pair(CR[1], CI[1], CR[3], CI[3], uAr, -uAip, \
                                -uBrp, uBi, uBrp, uBi, uAr, uAip); \
                     apply_pair(CR[0], CI[0], CR[1], CI[1], uAr, -uAip, \
                                -uBrp, uBi, uBrp, uBi, uAr, uAip); \
                     apply_pair(CR[2], CI[2], CR[3], CI[3], uAr, -uAip, \
                                -uBrp, uBi, uBrp, uBi, uAr, uAip); } while (0)
#define RING(RL45, VL70) do { ring_perm<RL45>(CR, CI, l); \
                              cnot_swap21(CR, CI); \
                              cnot_rl<VL70>(CR, CI); } while (0)

  // cycle 1 ring (U part replaced by closed form above)
  RING(31, 24);
  // cycle 2
  ULANE(16, 24); ULANE(24, 12); ULANE(28, 6);  ULANE(30, 3); ULANE(31, 1);
  UREGS(); RING(21, 20);
  // cycle 3
  ULANE(16, 20); ULANE(8, 10);  ULANE(20, 5);  ULANE(10, 2); ULANE(21, 1);
  UREGS(); RING(19, 30);
  // cycle 4
  ULANE(16, 30); ULANE(24, 15); ULANE(12, 7);  ULANE(6, 3);  ULANE(19, 1);
  UREGS(); RING(17, 17);
#undef RING
#undef UREGS
#undef ULANE

  // ---- QCNN section ----
#define LD(k) const float co##k = cs[2 * k], si##k = cs[2 * k + 1]
  LD(0); crx_ll<16, 8>(CR, CI, l, co0, si0);   // (0,1)
  LD(1); crx_ll<4, 2>(CR, CI, l, co1, si1);    // (2,3)
  LD(2); crx_lr4<17>(CR, CI, l, co2, si2);     // (4,5) pack-target
  LD(3);                                       // (6,7): ctrl bit1, tgt bit0
  crx_pairv(CR[2], CI[2], CR[3], CI[3], dup(co3), dup(si3), dup(-si3));
  LD(4); crx_ll<8, 4>(CR, CI, l, co4, si4);    // (1,2)
  LD(5); crx_ll<2, 1>(CR, CI, l, co5, si5);    // (3,4)
  LD(6);                                       // (5,6): ctrl pack -> half coeffs
  {
    const v2f cCC = (v2f){1.f, co6}, cSS = (v2f){0.f, si6}, cSSN = (v2f){0.f, -si6};
    crx_pairv(CR[0], CI[0], CR[2], CI[2], cCC, cSS, cSSN);
    crx_pairv(CR[1], CI[1], CR[3], CI[3], cCC, cSS, cSSN);
  }

  { G1 g = load_g1(cs, 0); u3_lane<8, 8>(CR, CI, l, g); }  // wire 1
  { G1 g = load_g1(cs, 1); u3_lane<2, 2>(CR, CI, l, g); }  // wire 3
  { G1 g = load_g1(cs, 2); u3_reg4(CR, CI, g); }           // wire 5 pack
  { G1 g = load_g1(cs, 3);                                 // wire 7 (bit0)
    apply_pair(CR[0], CI[0], CR[1], CI[1], g.r00, g.i00, g.r01, g.i01,
               g.r10, g.i10, g.r11, g.i11);
    apply_pair(CR[2], CI[2], CR[3], CI[3], g.r00, g.i00, g.r01, g.i01,
               g.r10, g.i10, g.r11, g.i11); }

  LD(7); crx_ll<8, 2>(CR, CI, l, co7, si7);    // (1,3)
  LD(8);                                       // (5,7): ctrl pack, tgt bit0
  {
    const v2f cCC = (v2f){1.f, co8}, cSS = (v2f){0.f, si8}, cSSN = (v2f){0.f, -si8};
    crx_pairv(CR[0], CI[0], CR[1], CI[1], cCC, cSS, cSSN);
    crx_pairv(CR[2], CI[2], CR[3], CI[3], cCC, cSS, cSSN);
  }
  LD(9); crx_lr4<2>(CR, CI, l, co9, si9);      // (3,5) pack-target

  { G1 g = load_g1(cs, 4); u3_lane<2, 2>(CR, CI, l, g); }  // wire 3
#undef LD

  // ---- folded measurement: ev = s^H M_c s, c = parity(l&2) ----
  {
    const bool cH = (l & 2) != 0;
    const float w00 = cH ? cs[84] : cs[80];
    const float w11 = cH ? cs[85] : cs[81];
    const float wa  = cH ? cs[86] : cs[82];
    const float wb  = cH ? cs[87] : cs[83];
    v2f PL = pkfma(CI[0], CI[0], pkmul(CR[0], CR[0]));
    PL = PL + pkfma(CI[2], CI[2], pkmul(CR[2], CR[2]));
    v2f PH = pkfma(CI[1], CI[1], pkmul(CR[1], CR[1]));
    PH = PH + pkfma(CI[3], CI[3], pkmul(CR[3], CR[3]));
    v2f X = pkfma(CI[0], CI[1], pkmul(CR[0], CR[1]));
    X = X + pkfma(CI[2], CI[3], pkmul(CR[2], CR[3]));
    v2f Y = pkmul(CR[0], CI[1]) - pkmul(CI[0], CR[1]);
    Y = Y + (pkmul(CR[2], CI[3]) - pkmul(CI[2], CR[3]));
    v2f EV = pkfma(dup(wb), Y, pkfma(dup(wa), X,
             pkfma(dup(w11), PH, pkmul(dup(w00), PL))));
    float v = EV.x + EV.y;
    v += shxm<1>(v); v += shxm<2>(v); v += shxm<4>(v);
    v += shxm<8>(v); v += shxm<16>(v);
    if (l == 0) out[b] = fmaxf(v, 0.f);
  }
}

extern "C" void kernel_launch(void* const* d_in, const int* in_sizes, int n_in,
                              void* d_out, int out_size, void* d_ws, size_t ws_size,
                              hipStream_t stream) {
  const float* theta = (const float*)d_in[0];
  const float* phi = (const float*)d_in[1];
  const float* crx = (const float*)d_in[2];
  const float* u3p = (const float*)d_in[3];
  float* out = (float*)d_out;
  float* ws = (float*)d_ws;
  const int nb = in_sizes[0];

  prep_kernel<<<1, 64, 0, stream>>>(crx, u3p, ws);

  const int elems_per_block = 8;  // 4 waves * 2 elements
  dim3 block(256);
  dim3 grid((nb + elems_per_block - 1) / elems_per_block);
  qcnn_kernel<<<grid, block, 0, stream>>>(theta, phi, ws, out, nb);
}

// Round 12
// 76.106 us; speedup vs baseline: 1.0166x; 1.0049x over previous
//
#include <hip/hip_runtime.h>
#include <math.h>

// FINAL = round-9 kernel verbatim (best measured: 75.27 us total).
// r10 (all-ds_swizzle) and r11 (ring_perm fusion) both regressed; this
// reverts to the empirically optimal variant.
//
// Layout: 8 complex amps/lane, 2 batch elements/wave64 (one per 32-lane
// half).  Amp p = l<<3 | r, l = lane&31 (5 lane bits, wires 0..4), r = reg
// (3 bits: bit2=wire5=pack axis, bit1=wire6, bit0=wire7).  Regs packed as
// float2 along reg bit2.  asm v_pk_* math (VOP3P, incl. op_sel variants);
// DPP for shuffle masks {1,2,3,7,8,15}, ds_swizzle otherwise; prep kernel
// for batch-invariant coefficients; cycle-1 closed-form product state;
// folded measurement (u3#5, crx10, u3#6, Z7 -> two 2x2 Hermitian forms).
//
// Lane-bit lazy GF(2) CNOT relabeling (validated r4..r9):
//  C2 U:(16,24)(24,12)(28,6)(30,3)(31,1) lr-ctrl 21  rl-V 20
//  C3 U:(16,20)(8,10)(20,5)(10,2)(21,1)  lr-ctrl 19  rl-V 30
//  C4 U:(16,30)(24,15)(12,7)(6,3)(19,1)  lr-ctrl 17  rl-V 17
//  QCNN: w0(16,17) w1(8,8) w2(4,4) w3(2,2) w4(17,1); reg wires 5,6,7=bits 2,1,0.

typedef float v2f __attribute__((ext_vector_type(2)));

__device__ __forceinline__ v2f pkmul(v2f a, v2f b) {
  v2f d; asm("v_pk_mul_f32 %0, %1, %2" : "=v"(d) : "v"(a), "v"(b)); return d;
}
__device__ __forceinline__ v2f pkfma(v2f a, v2f b, v2f c) {
  v2f d; asm("v_pk_fma_f32 %0, %1, %2, %3" : "=v"(d) : "v"(a), "v"(b), "v"(c)); return d;
}
__device__ __forceinline__ v2f pkmul_lo1(v2f a, v2f b) {
  v2f d; asm("v_pk_mul_f32 %0, %1, %2 op_sel:[0,0] op_sel_hi:[1,0]"
             : "=v"(d) : "v"(a), "v"(b)); return d;
}
__device__ __forceinline__ v2f pkfma_lo1(v2f a, v2f b, v2f c) {
  v2f d; asm("v_pk_fma_f32 %0, %1, %2, %3 op_sel:[0,0,0] op_sel_hi:[1,0,1]"
             : "=v"(d) : "v"(a), "v"(b), "v"(c)); return d;
}
__device__ __forceinline__ v2f pkfma_hi1(v2f a, v2f b, v2f c) {
  v2f d; asm("v_pk_fma_f32 %0, %1, %2, %3 op_sel:[0,1,0] op_sel_hi:[1,1,1]"
             : "=v"(d) : "v"(a), "v"(b), "v"(c)); return d;
}
__device__ __forceinline__ v2f pkfma_sw1(v2f a, v2f b, v2f c) {
  v2f d; asm("v_pk_fma_f32 %0, %1, %2, %3 op_sel:[0,1,0] op_sel_hi:[1,0,1]"
             : "=v"(d) : "v"(a), "v"(b), "v"(c)); return d;
}
__device__ __forceinline__ v2f dup(float x) { return (v2f){x, x}; }

template <int M>
__device__ __forceinline__ float shxm(float v) {
  if constexpr (M == 1 || M == 2 || M == 3 || M == 7 || M == 8 || M == 15) {
    constexpr int ctrl = (M == 1) ? 0xB1 : (M == 2) ? 0x4E : (M == 3) ? 0x1B
                         : (M == 7) ? 0x141 : (M == 8) ? 0x128 : 0x140;
    return __int_as_float(__builtin_amdgcn_update_dpp(
        0, __float_as_int(v), ctrl, 0xF, 0xF, true));
  } else {
    return __int_as_float(__builtin_amdgcn_ds_swizzle(
        __float_as_int(v), (M << 10) | 0x1F));
  }
}
template <int M>
__device__ __forceinline__ v2f shf2(v2f a) {
  return (v2f){shxm<M>(a.x), shxm<M>(a.y)};
}

struct G1 { float r00, i00, r01, i01, r10, i10, r11, i11; };

// generic 2x2 complex gate on a reg pair (lo,hi) across two packs.
__device__ __forceinline__ void apply_pair(v2f& LR, v2f& LI, v2f& HR, v2f& HI,
                                           float g00r, float g00i, float g01r,
                                           float g01i, float g10r, float g10i,
                                           float g11r, float g11i) {
  const v2f a00r = dup(g00r), a00i = dup(g00i), n00i = dup(-g00i);
  const v2f a01r = dup(g01r), a01i = dup(g01i), n01i = dup(-g01i);
  const v2f a10r = dup(g10r), a10i = dup(g10i), n10i = dup(-g10i);
  const v2f a11r = dup(g11r), a11i = dup(g11i), n11i = dup(-g11i);
  v2f NLR = pkfma(n01i, HI, pkfma(a01r, HR, pkfma(n00i, LI, pkmul(a00r, LR))));
  v2f NLI = pkfma(a01i, HR, pkfma(a01r, HI, pkfma(a00i, LR, pkmul(a00r, LI))));
  v2f NHR = pkfma(n11i, HI, pkfma(a11r, HR, pkfma(n10i, LI, pkmul(a10r, LR))));
  v2f NHI = pkfma(a11i, HR, pkfma(a11r, HI, pkfma(a10i, LR, pkmul(a10r, LI))));
  LR = NLR; LI = NLI; HR = NHR; HI = NHI;
}

__device__ __forceinline__ void crx_pairv(v2f& LR, v2f& LI, v2f& HR, v2f& HI,
                                          v2f cCC, v2f cSS, v2f cSSN) {
  v2f NLR = pkfma(cSS, HI, pkmul(cCC, LR));
  v2f NLI = pkfma(cSSN, HR, pkmul(cCC, LI));
  v2f NHR = pkfma(cSS, LI, pkmul(cCC, HR));
  v2f NHI = pkfma(cSSN, LR, pkmul(cCC, HI));
  LR = NLR; LI = NLI; HR = NHR; HI = NHI;
}

// U = RZ@RY on a lane bit (fully packed).
template <int RL, int VL>
__device__ __forceinline__ void u_lane(v2f (&CR)[4], v2f (&CI)[4], int l,
                                       float uAr, float uBi, float uAip,
                                       float uBrp) {
  const bool hi = (__popc(l & RL) & 1) != 0;
  const float Ai = hi ? uAip : -uAip;
  const float Br = hi ? uBrp : -uBrp;
  const v2f cAr = dup(uAr), cAi = dup(Ai), cAiN = dup(-Ai);
  const v2f cBr = dup(Br), cBi = dup(uBi), cBiN = dup(-uBi);
  v2f PR[4], PI[4];
#pragma unroll
  for (int q = 0; q < 4; ++q) { PR[q] = shf2<VL>(CR[q]); PI[q] = shf2<VL>(CI[q]); }
#pragma unroll
  for (int q = 0; q < 4; ++q) {
    v2f NR = pkfma(cBiN, PI[q], pkfma(cBr, PR[q], pkfma(cAiN, CI[q], pkmul(cAr, CR[q]))));
    v2f NI = pkfma(cBi, PR[q], pkfma(cBr, PI[q], pkfma(cAi, CR[q], pkmul(cAr, CI[q]))));
    CR[q] = NR; CI[q] = NI;
  }
}

// generic 2x2 gate on the PACK axis via op_sel (8 pk per pack).
__device__ __forceinline__ void gate_pack(v2f (&CR)[4], v2f (&CI)[4],
                                          v2f cA, v2f cB, v2f cBn,
                                          v2f cC, v2f cD, v2f cDn) {
#pragma unroll
  for (int q = 0; q < 4; ++q) {
    v2f NR = pkfma_hi1(cDn, CI[q], pkfma_hi1(cC, CR[q],
             pkfma_lo1(cBn, CI[q], pkmul_lo1(cA, CR[q]))));
    v2f NI = pkfma_hi1(cD, CR[q], pkfma_hi1(cC, CI[q],
             pkfma_lo1(cB, CR[q], pkmul_lo1(cA, CI[q]))));
    CR[q] = NR; CI[q] = NI;
  }
}

__device__ __forceinline__ void u_reg4(v2f (&CR)[4], v2f (&CI)[4], float uAr,
                                       float uBi, float uAip, float uBrp) {
  gate_pack(CR, CI,
            (v2f){uAr, uBrp}, (v2f){-uAip, uBi}, (v2f){uAip, -uBi},
            (v2f){-uBrp, uAr}, (v2f){uBi, uAip}, (v2f){-uBi, -uAip});
}

__device__ __forceinline__ void u3_reg4(v2f (&CR)[4], v2f (&CI)[4], const G1& g) {
  gate_pack(CR, CI,
            (v2f){g.r00, g.r10}, (v2f){g.i00, g.i10}, (v2f){-g.i00, -g.i10},
            (v2f){g.r01, g.r11}, (v2f){g.i01, g.i11}, (v2f){-g.i01, -g.i11});
}

// ring CNOT (4,5): lane ctrl -> conditional .x/.y swap.
template <int RL>
__device__ __forceinline__ void cnot_lr4(v2f (&CR)[4], v2f (&CI)[4], int l) {
  const bool c = (__popc(l & RL) & 1) != 0;
#pragma unroll
  for (int q = 0; q < 4; ++q) {
    const float ax = CR[q].x, ay = CR[q].y;
    CR[q] = (v2f){c ? ay : ax, c ? ax : ay};
    const float bx = CI[q].x, by = CI[q].y;
    CI[q] = (v2f){c ? by : bx, c ? bx : by};
  }
}

__device__ __forceinline__ void cnot_swap42(v2f (&CR)[4], v2f (&CI)[4]) {
  float t;
  t = CR[0].y; CR[0].y = CR[2].y; CR[2].y = t;
  t = CR[1].y; CR[1].y = CR[3].y; CR[3].y = t;
  t = CI[0].y; CI[0].y = CI[2].y; CI[2].y = t;
  t = CI[1].y; CI[1].y = CI[3].y; CI[3].y = t;
}

__device__ __forceinline__ void cnot_swap21(v2f (&CR)[4], v2f (&CI)[4]) {
  v2f t;
  t = CR[2]; CR[2] = CR[3]; CR[3] = t;
  t = CI[2]; CI[2] = CI[3]; CI[3] = t;
}

template <int VL>
__device__ __forceinline__ void cnot_rl(v2f (&CR)[4], v2f (&CI)[4]) {
  CR[1] = shf2<VL>(CR[1]); CI[1] = shf2<VL>(CI[1]);
  CR[3] = shf2<VL>(CR[3]); CI[3] = shf2<VL>(CI[3]);
}

template <int RL, int VL>
__device__ __forceinline__ void crx_ll(v2f (&CR)[4], v2f (&CI)[4], int l,
                                       float co, float si) {
  const bool c = (__popc(l & RL) & 1) != 0;
  const float cc = c ? co : 1.f, ss = c ? si : 0.f;
  const v2f cCC = dup(cc), cSS = dup(ss), cSSN = dup(-ss);
  v2f PR[4], PI[4];
#pragma unroll
  for (int q = 0; q < 4; ++q) { PR[q] = shf2<VL>(CR[q]); PI[q] = shf2<VL>(CI[q]); }
#pragma unroll
  for (int q = 0; q < 4; ++q) {
    CR[q] = pkfma(cSS, PI[q], pkmul(cCC, CR[q]));
    CI[q] = pkfma(cSSN, PR[q], pkmul(cCC, CI[q]));
  }
}

template <int RL>
__device__ __forceinline__ void crx_lr4(v2f (&CR)[4], v2f (&CI)[4], int l,
                                        float co, float si) {
  const bool c = (__popc(l & RL) & 1) != 0;
  const float cc = c ? co : 1.f, ss = c ? si : 0.f;
  const v2f cc2 = dup(cc), ss2 = dup(ss), ssN2 = dup(-ss);
#pragma unroll
  for (int q = 0; q < 4; ++q) {
    v2f NR = pkfma_sw1(ss2, CI[q], pkmul(cc2, CR[q]));
    v2f NI = pkfma_sw1(ssN2, CR[q], pkmul(cc2, CI[q]));
    CR[q] = NR; CI[q] = NI;
  }
}

template <int RL, int VL>
__device__ __forceinline__ void u3_lane(v2f (&CR)[4], v2f (&CI)[4], int l,
                                        const G1& g) {
  const bool hi = (__popc(l & RL) & 1) != 0;
  const float Ar = hi ? g.r11 : g.r00, Aii = hi ? g.i11 : g.i00;
  const float Br = hi ? g.r10 : g.r01, Bi = hi ? g.i10 : g.i01;
  const v2f cAr = dup(Ar), cAi = dup(Aii), cAiN = dup(-Aii);
  const v2f cBr = dup(Br), cBi = dup(Bi), cBiN = dup(-Bi);
  v2f PR[4], PI[4];
#pragma unroll
  for (int q = 0; q < 4; ++q) { PR[q] = shf2<VL>(CR[q]); PI[q] = shf2<VL>(CI[q]); }
#pragma unroll
  for (int q = 0; q < 4; ++q) {
    v2f NR = pkfma(cBiN, PI[q], pkfma(cBr, PR[q], pkfma(cAiN, CI[q], pkmul(cAr, CR[q]))));
    v2f NI = pkfma(cBi, PR[q], pkfma(cBr, PI[q], pkfma(cAi, CR[q], pkmul(cAr, CI[q]))));
    CR[q] = NR; CI[q] = NI;
  }
}

__device__ __forceinline__ G1 load_g1(const float* __restrict__ cs, int k) {
  const float* p = cs + 22 + 8 * k;
  G1 g;
  g.r00 = p[0]; g.i00 = p[1]; g.r01 = p[2]; g.i01 = p[3];
  g.r10 = p[4]; g.i10 = p[5]; g.r11 = p[6]; g.i11 = p[7];
  return g;
}

// ---- prep: batch-invariant coefficients -> d_ws ----
struct Cx { float r, i; };
__device__ __forceinline__ Cx cmul(Cx a, Cx b) {
  return {a.r * b.r - a.i * b.i, a.r * b.i + a.i * b.r};
}
__device__ __forceinline__ Cx cconj(Cx a) { return {a.r, -a.i}; }
__device__ __forceinline__ Cx cadd(Cx a, Cx b) { return {a.r + b.r, a.i + b.i}; }
__device__ __forceinline__ Cx csub(Cx a, Cx b) { return {a.r - b.r, a.i - b.i}; }
__device__ __forceinline__ Cx cscale(float s, Cx a) { return {s * a.r, s * a.i}; }

__device__ void congr(float n00, Cx n01, float n11, Cx G00, Cx G01, Cx G10,
                      Cx G11, float& m00, Cx& m01, float& m11) {
  Cx t0 = cadd(cscale(n00, G00), cmul(n01, G10));
  Cx t1 = cadd(cmul(cconj(n01), G00), cscale(n11, G10));
  Cx u0 = cadd(cscale(n00, G01), cmul(n01, G11));
  Cx u1 = cadd(cmul(cconj(n01), G01), cscale(n11, G11));
  m00 = cadd(cmul(cconj(G00), t0), cmul(cconj(G10), t1)).r;
  m01 = cadd(cmul(cconj(G00), u0), cmul(cconj(G10), u1));
  m11 = cadd(cmul(cconj(G01), u0), cmul(cconj(G11), u1)).r;
}

__device__ void build_u3(float t, float p, float l, Cx& G00, Cx& G01, Cx& G10,
                         Cx& G11) {
  float st, ct, sp, cp, sl, cl;
  sincosf(0.5f * t, &st, &ct);
  sincosf(p, &sp, &cp);
  sincosf(l, &sl, &cl);
  G00 = {ct, 0.f};
  G01 = {-cl * st, -sl * st};
  G10 = {cp * st, sp * st};
  G11 = {(cp * cl - sp * sl) * ct, (sp * cl + cp * sl) * ct};
}

__global__ void prep_kernel(const float* __restrict__ crx,
                            const float* __restrict__ u3p,
                            float* __restrict__ ws) {
  const int t = threadIdx.x;
  if (t < 11) {
    float s, c;
    sincosf(0.5f * crx[t], &s, &c);
    ws[2 * t] = c; ws[2 * t + 1] = s;
  } else if (t >= 16 && t < 23) {
    const int k = t - 16;
    float st, ct, sp, cp, sl, cl;
    sincosf(0.5f * u3p[3 * k], &st, &ct);
    sincosf(u3p[3 * k + 1], &sp, &cp);
    sincosf(u3p[3 * k + 2], &sl, &cl);
    float* o = ws + 22 + 8 * k;
    o[0] = ct;            o[1] = 0.f;
    o[2] = -cl * st;      o[3] = -sl * st;
    o[4] = cp * st;       o[5] = sp * st;
    o[6] = (cp * cl - sp * sl) * ct;
    o[7] = (sp * cl + cp * sl) * ct;
  } else if (t == 30) {
    // folded measurement matrices (u3#5, crx10, u3#6, Z7)
    Cx A00, A01, A10, A11, C00, C01, C10, C11;
    build_u3(u3p[15], u3p[16], u3p[17], A00, A01, A10, A11);  // u3 gate 5
    build_u3(u3p[18], u3p[19], u3p[20], C00, C01, C10, C11);  // u3 gate 6
    float n00 = (C00.r * C00.r + C00.i * C00.i) - (C10.r * C10.r + C10.i * C10.i);
    Cx n01 = csub(cmul(cconj(C00), C01), cmul(cconj(C10), C11));
    float n11 = (C01.r * C01.r + C01.i * C01.i) - (C11.r * C11.r + C11.i * C11.i);
    float m00, m11; Cx m01;
    congr(n00, n01, n11, A00, A01, A10, A11, m00, m01, m11);
    ws[80] = m00; ws[81] = m11; ws[82] = 2.f * m01.r; ws[83] = -2.f * m01.i;
    float co, si;
    sincosf(0.5f * crx[10], &si, &co);
    Cx R00 = {co, 0.f}, R01 = {0.f, -si}, R10 = {0.f, -si}, R11 = {co, 0.f};
    float p00, p11; Cx p01;
    congr(n00, n01, n11, R00, R01, R10, R11, p00, p01, p11);
    congr(p00, p01, p11, A00, A01, A10, A11, m00, m01, m11);
    ws[84] = m00; ws[85] = m11; ws[86] = 2.f * m01.r; ws[87] = -2.f * m01.i;
  }
}

__global__ __launch_bounds__(256, 4) void qcnn_kernel(
    const float* __restrict__ theta, const float* __restrict__ phi,
    const float* __restrict__ cs, float* __restrict__ out, int nbatch) {
  const int tid = blockIdx.x * blockDim.x + threadIdx.x;
  const int wave = tid >> 6;
  const int lane = threadIdx.x & 63;
  const int l = lane & 31;
  int b = wave * 2 + (lane >> 5);
  if (b >= nbatch) b = nbatch - 1;

  float sth, cth, sph, cph;
  __sincosf(0.5f * theta[b], &sth, &cth);
  __sincosf(0.5f * phi[b], &sph, &cph);
  const float uAr = cph * cth, uBi = sph * sth;
  const float uAip = sph * cth, uBrp = cph * sth;

  // ---- cycle-1 closed form: amp(x) = g0^(8-k) g1^k, k = popc(x) ----
  const float g0r = uAr, g0i = -uAip, g1r = uBrp, g1i = uBi;
  float Zr = (l & 16) ? g1r : g0r, Zi = (l & 16) ? g1i : g0i;
#define MULBIT(m)                                                     \
  {                                                                   \
    const float Fr = (l & m) ? g1r : g0r, Fi = (l & m) ? g1i : g0i;   \
    const float nr = Zr * Fr - Zi * Fi, ni = Zr * Fi + Zi * Fr;       \
    Zr = nr; Zi = ni;                                                 \
  }
  MULBIT(8) MULBIT(4) MULBIT(2) MULBIT(1)
#undef MULBIT
  const float g00r = g0r * g0r - g0i * g0i, g00i = 2.f * g0r * g0i;
  const float g11r = g1r * g1r - g1i * g1i, g11i = 2.f * g1r * g1i;
  const float h0r = g00r * g0r - g00i * g0i, h0i = g00r * g0i + g00i * g0r;
  const float h1r = g00r * g1r - g00i * g1i, h1i = g00r * g1i + g00i * g1r;
  const float h2r = g11r * g0r - g11i * g0i, h2i = g11r * g0i + g11i * g0r;
  const float h3r = g11r * g1r - g11i * g1i, h3i = g11r * g1i + g11i * g1r;

  v2f CR[4], CI[4];
  {
    const v2f Zrv = dup(Zr), Ziv = dup(Zi), ZivN = dup(-Zi);
    const v2f Hr[4] = {{h0r, h1r}, {h1r, h2r}, {h1r, h2r}, {h2r, h3r}};
    const v2f Hi[4] = {{h0i, h1i}, {h1i, h2i}, {h1i, h2i}, {h2i, h3i}};
#pragma unroll
    for (int q = 0; q < 4; ++q) {
      CR[q] = pkfma(ZivN, Hi[q], pkmul(Zrv, Hr[q]));
      CI[q] = pkfma(Ziv, Hr[q], pkmul(Zrv, Hi[q]));
    }
  }

#define ULANE(RL, VL) u_lane<RL, VL>(CR, CI, l, uAr, uBi, uAip, uBrp)
#define UREGS() do { u_reg4(CR, CI, uAr, uBi, uAip, uBrp); \
                     apply_pair(CR[0], CI[0], CR[2], CI[2], uAr, -uAip, \
                                -uBrp, uBi, uBrp, uBi, uAr, uAip); \
                     apply_pair(CR[1], CI[1], CR[3], CI[3], uAr, -uAip, \
                                -uBrp, uBi, uBrp, uBi, uAr, uAip); \
                     apply_pair(CR[0], CI[0], CR[1], CI[1], uAr, -uAip, \
                                -uBrp, uBi, uBrp, uBi, uAr, uAip); \
                     apply_pair(CR[2], CI[2], CR[3], CI[3], uAr, -uAip, \
                                -uBrp, uBi, uBrp, uBi, uAr, uAip); } while (0)
#define RING(RL45, VL70) do { cnot_lr4<RL45>(CR, CI, l); \
                              cnot_swap42(CR, CI); cnot_swap21(CR, CI); \
                              cnot_rl<VL70>(CR, CI); } while (0)

  // cycle 1 ring (U part replaced by closed form above)
  RING(31, 24);
  // cycle 2
  ULANE(16, 24); ULANE(24, 12); ULANE(28, 6);  ULANE(30, 3); ULANE(31, 1);
  UREGS(); RING(21, 20);
  // cycle 3
  ULANE(16, 20); ULANE(8, 10);  ULANE(20, 5);  ULANE(10, 2); ULANE(21, 1);
  UREGS(); RING(19, 30);
  // cycle 4
  ULANE(16, 30); ULANE(24, 15); ULANE(12, 7);  ULANE(6, 3);  ULANE(19, 1);
  UREGS(); RING(17, 17);
#undef RING
#undef UREGS
#undef ULANE

  // ---- QCNN section ----
#define LD(k) const float co##k = cs[2 * k], si##k = cs[2 * k + 1]
  LD(0); crx_ll<16, 8>(CR, CI, l, co0, si0);   // (0,1)
  LD(1); crx_ll<4, 2>(CR, CI, l, co1, si1);    // (2,3)
  LD(2); crx_lr4<17>(CR, CI, l, co2, si2);     // (4,5) pack-target
  LD(3);                                       // (6,7): ctrl bit1, tgt bit0
  crx_pairv(CR[2], CI[2], CR[3], CI[3], dup(co3), dup(si3), dup(-si3));
  LD(4); crx_ll<8, 4>(CR, CI, l, co4, si4);    // (1,2)
  LD(5); crx_ll<2, 1>(CR, CI, l, co5, si5);    // (3,4)
  LD(6);                                       // (5,6): ctrl pack -> half coeffs
  {
    const v2f cCC = (v2f){1.f, co6}, cSS = (v2f){0.f, si6}, cSSN = (v2f){0.f, -si6};
    crx_pairv(CR[0], CI[0], CR[2], CI[2], cCC, cSS, cSSN);
    crx_pairv(CR[1], CI[1], CR[3], CI[3], cCC, cSS, cSSN);
  }

  { G1 g = load_g1(cs, 0); u3_lane<8, 8>(CR, CI, l, g); }  // wire 1
  { G1 g = load_g1(cs, 1); u3_lane<2, 2>(CR, CI, l, g); }  // wire 3
  { G1 g = load_g1(cs, 2); u3_reg4(CR, CI, g); }           // wire 5 pack
  { G1 g = load_g1(cs, 3);                                 // wire 7 (bit0)
    apply_pair(CR[0], CI[0], CR[1], CI[1], g.r00, g.i00, g.r01, g.i01,
               g.r10, g.i10, g.r11, g.i11);
    apply_pair(CR[2], CI[2], CR[3], CI[3], g.r00, g.i00, g.r01, g.i01,
               g.r10, g.i10, g.r11, g.i11); }

  LD(7); crx_ll<8, 2>(CR, CI, l, co7, si7);    // (1,3)
  LD(8);                                       // (5,7): ctrl pack, tgt bit0
  {
    const v2f cCC = (v2f){1.f, co8}, cSS = (v2f){0.f, si8}, cSSN = (v2f){0.f, -si8};
    crx_pairv(CR[0], CI[0], CR[1], CI[1], cCC, cSS, cSSN);
    crx_pairv(CR[2], CI[2], CR[3], CI[3], cCC, cSS, cSSN);
  }
  LD(9); crx_lr4<2>(CR, CI, l, co9, si9);      // (3,5) pack-target

  { G1 g = load_g1(cs, 4); u3_lane<2, 2>(CR, CI, l, g); }  // wire 3
#undef LD

  // ---- folded measurement: ev = s^H M_c s, c = parity(l&2) ----
  {
    const bool cH = (l & 2) != 0;
    const float w00 = cH ? cs[84] : cs[80];
    const float w11 = cH ? cs[85] : cs[81];
    const float wa  = cH ? cs[86] : cs[82];
    const float wb  = cH ? cs[87] : cs[83];
    v2f PL = pkfma(CI[0], CI[0], pkmul(CR[0], CR[0]));
    PL = PL + pkfma(CI[2], CI[2], pkmul(CR[2], CR[2]));
    v2f PH = pkfma(CI[1], CI[1], pkmul(CR[1], CR[1]));
    PH = PH + pkfma(CI[3], CI[3], pkmul(CR[3], CR[3]));
    v2f X = pkfma(CI[0], CI[1], pkmul(CR[0], CR[1]));
    X = X + pkfma(CI[2], CI[3], pkmul(CR[2], CR[3]));
    v2f Y = pkmul(CR[0], CI[1]) - pkmul(CI[0], CR[1]);
    Y = Y + (pkmul(CR[2], CI[3]) - pkmul(CI[2], CR[3]));
    v2f EV = pkfma(dup(wb), Y, pkfma(dup(wa), X,
             pkfma(dup(w11), PH, pkmul(dup(w00), PL))));
    float v = EV.x + EV.y;
    v += shxm<1>(v); v += shxm<2>(v); v += shxm<4>(v);
    v += shxm<8>(v); v += shxm<16>(v);
    if (l == 0) out[b] = fmaxf(v, 0.f);
  }
}

extern "C" void kernel_launch(void* const* d_in, const int* in_sizes, int n_in,
                              void* d_out, int out_size, void* d_ws, size_t ws_size,
                              hipStream_t stream) {
  const float* theta = (const float*)d_in[0];
  const float* phi = (const float*)d_in[1];
  const float* crx = (const float*)d_in[2];
  const float* u3p = (const float*)d_in[3];
  float* out = (float*)d_out;
  float* ws = (float*)d_ws;
  const int nb = in_sizes[0];

  prep_kernel<<<1, 64, 0, stream>>>(crx, u3p, ws);

  const int elems_per_block = 8;  // 4 waves * 2 elements
  dim3 block(256);
  dim3 grid((nb + elems_per_block - 1) / elems_per_block);
  qcnn_kernel<<<grid, block, 0, stream>>>(theta, phi, ws, out, nb);
}